// Round 1
// baseline (1498.194 us; speedup 1.0000x reference)
//
#include <hip/hip_runtime.h>

constexpr int N_NODES = 50000;
constexpr int N_EDGES = 800000;
constexpr int D = 128;
constexpr float ALPHA = 0.2f;
constexpr int GROUPS = N_NODES / 8;   // 6250 groups of 8 nodes

// ---------------------------------------------------------------------------
// K1: h = feat @ W + bias;  s_src[n] = h[n]·a[:128];  s_dst[n] = h[n]·a[128:]
// Block = 256 threads = 8 nodes/iter; thread owns node (tid>>5), cols (tid&31)*4..+3.
// W staged in LDS as float4[k][cg] (64 KB). feat row value broadcast across the
// 32 lanes of a node-group (L1 broadcast).
// ---------------------------------------------------------------------------
__global__ __launch_bounds__(256)
void k_gemm_scores(const float* __restrict__ feat,
                   const float* __restrict__ W,
                   const float* __restrict__ a,
                   const float* __restrict__ bias,
                   float* __restrict__ h,
                   float* __restrict__ s_src,
                   float* __restrict__ s_dst)
{
    __shared__ float4 w_lds[D * 32];                 // 64 KB: [k][cg]
    const int tid = threadIdx.x;
    const float4* W4 = reinterpret_cast<const float4*>(W);
    for (int i = tid; i < D * 32; i += 256)          // row-major [k][c] == [k][cg] in float4
        w_lds[i] = W4[i];
    __syncthreads();

    const int cg = tid & 31;                         // column group (float4 index)
    const int ln = tid >> 5;                         // local node 0..7
    const float4 a_s = reinterpret_cast<const float4*>(a)[cg];
    const float4 a_d = reinterpret_cast<const float4*>(a)[32 + cg];
    const float4 b4  = reinterpret_cast<const float4*>(bias)[cg];

    for (int g = blockIdx.x; g < GROUPS; g += gridDim.x) {
        const int n = g * 8 + ln;
        const float* frow = feat + (long long)n * D;
        float4 acc = {0.f, 0.f, 0.f, 0.f};
        #pragma unroll 8
        for (int k = 0; k < D; ++k) {
            const float  f  = frow[k];               // broadcast across 32 lanes
            const float4 w4 = w_lds[k * 32 + cg];    // consecutive 16B chunks: conflict-free
            acc.x += f * w4.x; acc.y += f * w4.y;
            acc.z += f * w4.z; acc.w += f * w4.w;
        }
        acc.x += b4.x; acc.y += b4.y; acc.z += b4.z; acc.w += b4.w;
        reinterpret_cast<float4*>(h)[(long long)n * 32 + cg] = acc;

        float ps = acc.x * a_s.x + acc.y * a_s.y + acc.z * a_s.z + acc.w * a_s.w;
        float pd = acc.x * a_d.x + acc.y * a_d.y + acc.z * a_d.z + acc.w * a_d.w;
        #pragma unroll
        for (int m = 1; m < 32; m <<= 1) {           // reduce within the 32-lane node group
            ps += __shfl_xor(ps, m);
            pd += __shfl_xor(pd, m);
        }
        if (cg == 0) { s_src[n] = ps; s_dst[n] = pd; }
    }
}

// ---------------------------------------------------------------------------
// K2: per-edge attention logit e = leaky_relu(s_src[src] + s_dst[dst])
// ---------------------------------------------------------------------------
__global__ __launch_bounds__(256)
void k_edge_scores(const int* __restrict__ adj,
                   const float* __restrict__ s_src,
                   const float* __restrict__ s_dst,
                   float* __restrict__ e)
{
    const int i = blockIdx.x * 256 + threadIdx.x;
    if (i < N_EDGES) {
        const int s = adj[i];
        const int d = adj[N_EDGES + i];
        const float x = s_src[s] + s_dst[d];
        e[i] = x > 0.f ? x : ALPHA * x;
    }
}

// ---------------------------------------------------------------------------
// K3: out[src] += e * h[dst]   (32 threads per edge, float4 per thread)
// ---------------------------------------------------------------------------
__global__ __launch_bounds__(256)
void k_scatter(const int* __restrict__ adj,
               const float* __restrict__ e,
               const float* __restrict__ h,
               float* __restrict__ out)
{
    const int t    = blockIdx.x * 256 + threadIdx.x; // < 25.6M
    const int edge = t >> 5;
    const int cg   = t & 31;
    const int s  = adj[edge];
    const int d  = adj[N_EDGES + edge];
    const float ev = e[edge];
    const float4 hv = reinterpret_cast<const float4*>(h)[(long long)d * 32 + cg];
    float* op = out + (long long)s * D + cg * 4;
    atomicAdd(op + 0, ev * hv.x);
    atomicAdd(op + 1, ev * hv.y);
    atomicAdd(op + 2, ev * hv.z);
    atomicAdd(op + 3, ev * hv.w);
}

// ---------------------------------------------------------------------------
extern "C" void kernel_launch(void* const* d_in, const int* in_sizes, int n_in,
                              void* d_out, int out_size, void* d_ws, size_t ws_size,
                              hipStream_t stream) {
    const float* feat = (const float*)d_in[0];
    const float* W    = (const float*)d_in[1];
    const float* a    = (const float*)d_in[2];
    const float* bias = (const float*)d_in[3];
    const int*   adj  = (const int*)d_in[4];
    float* out = (float*)d_out;

    char* ws = (char*)d_ws;
    float* h     = (float*)(ws);                       // 25,600,000 B
    float* s_src = (float*)(ws + 25600000);            //    200,000 B
    float* s_dst = (float*)(ws + 25800000);            //    200,000 B
    float* e     = (float*)(ws + 26000000);            //  3,200,000 B

    hipMemsetAsync(d_out, 0, (size_t)N_NODES * D * sizeof(float), stream);

    k_gemm_scores<<<2048, 256, 0, stream>>>(feat, W, a, bias, h, s_src, s_dst);
    k_edge_scores<<<(N_EDGES + 255) / 256, 256, 0, stream>>>(adj, s_src, s_dst, e);
    k_scatter<<<(N_EDGES * 32) / 256, 256, 0, stream>>>(adj, e, h, out);
}

// Round 2
// 397.161 us; speedup vs baseline: 3.7723x; 3.7723x over previous
//
#include <hip/hip_runtime.h>

constexpr int N_NODES = 50000;
constexpr int N_EDGES = 800000;
constexpr int D = 128;
constexpr float ALPHA = 0.2f;
constexpr int GROUPS = N_NODES / 8;   // 6250 groups of 8 nodes (gemm)

// ---------------------------------------------------------------------------
// K1: h = feat @ W + bias;  s_src[n] = h[n]·a[:128];  s_dst[n] = h[n]·a[128:]
// ---------------------------------------------------------------------------
__global__ __launch_bounds__(256)
void k_gemm_scores(const float* __restrict__ feat,
                   const float* __restrict__ W,
                   const float* __restrict__ a,
                   const float* __restrict__ bias,
                   float* __restrict__ h,
                   float* __restrict__ s_src,
                   float* __restrict__ s_dst)
{
    __shared__ float4 w_lds[D * 32];                 // 64 KB: [k][cg]
    const int tid = threadIdx.x;
    const float4* W4 = reinterpret_cast<const float4*>(W);
    for (int i = tid; i < D * 32; i += 256)
        w_lds[i] = W4[i];
    __syncthreads();

    const int cg = tid & 31;                         // column group (float4 index)
    const int ln = tid >> 5;                         // local node 0..7
    const float4 a_s = reinterpret_cast<const float4*>(a)[cg];
    const float4 a_d = reinterpret_cast<const float4*>(a)[32 + cg];
    const float4 b4  = reinterpret_cast<const float4*>(bias)[cg];

    for (int g = blockIdx.x; g < GROUPS; g += gridDim.x) {
        const int n = g * 8 + ln;
        const float* frow = feat + (long long)n * D;
        float4 acc = {0.f, 0.f, 0.f, 0.f};
        #pragma unroll 8
        for (int k = 0; k < D; ++k) {
            const float  f  = frow[k];               // broadcast across 32 lanes
            const float4 w4 = w_lds[k * 32 + cg];
            acc.x += f * w4.x; acc.y += f * w4.y;
            acc.z += f * w4.z; acc.w += f * w4.w;
        }
        acc.x += b4.x; acc.y += b4.y; acc.z += b4.z; acc.w += b4.w;
        reinterpret_cast<float4*>(h)[(long long)n * 32 + cg] = acc;

        float ps = acc.x * a_s.x + acc.y * a_s.y + acc.z * a_s.z + acc.w * a_s.w;
        float pd = acc.x * a_d.x + acc.y * a_d.y + acc.z * a_d.z + acc.w * a_d.w;
        #pragma unroll
        for (int m = 1; m < 32; m <<= 1) {
            ps += __shfl_xor(ps, m);
            pd += __shfl_xor(pd, m);
        }
        if (cg == 0) { s_src[n] = ps; s_dst[n] = pd; }
    }
}

// ---------------------------------------------------------------------------
// K2a: histogram edges by src
// ---------------------------------------------------------------------------
__global__ __launch_bounds__(256)
void k_hist(const int* __restrict__ adj, int* __restrict__ counts)
{
    const int i = blockIdx.x * 256 + threadIdx.x;
    if (i < N_EDGES) atomicAdd(&counts[adj[i]], 1);
}

// ---------------------------------------------------------------------------
// K2b: exclusive scan of counts -> row_start, cursor (single block, 1024 thr)
// ---------------------------------------------------------------------------
__global__ __launch_bounds__(1024)
void k_scan(const int* __restrict__ counts,
            int* __restrict__ row_start,
            int* __restrict__ cursor)
{
    __shared__ int part[1024];
    const int t = threadIdx.x;
    const int CH = (N_NODES + 1023) / 1024;          // 49
    const int beg = t * CH;
    const int end = min(beg + CH, N_NODES);
    int sum = 0;
    for (int i = beg; i < end; ++i) sum += counts[i];
    part[t] = sum;
    __syncthreads();
    int incl = sum;
    for (int off = 1; off < 1024; off <<= 1) {
        const int other = (t >= off) ? part[t - off] : 0;
        __syncthreads();
        part[t] += other;
        __syncthreads();
        incl = part[t];
    }
    int running = incl - sum;                        // exclusive base for this chunk
    for (int i = beg; i < end; ++i) {
        row_start[i] = running;
        cursor[i]    = running;
        running += counts[i];
    }
}

// ---------------------------------------------------------------------------
// K2c: bucket fill — col[pos] = dst for each edge, bucketed by src
// ---------------------------------------------------------------------------
__global__ __launch_bounds__(256)
void k_fill(const int* __restrict__ adj,
            int* __restrict__ cursor,
            int* __restrict__ col)
{
    const int i = blockIdx.x * 256 + threadIdx.x;
    if (i < N_EDGES) {
        const int s = adj[i];
        const int d = adj[N_EDGES + i];
        const int pos = atomicAdd(&cursor[s], 1);
        col[pos] = d;
    }
}

// ---------------------------------------------------------------------------
// K3: gather — out[n] = sum over edges(n) of leaky(ss[n]+sd[dst]) * h[dst]
// 32 lanes per node, float4 per lane. One coalesced 512B store per node.
// After k_fill, cursor[n] == row_start[n] + deg[n] == end of n's bucket.
// ---------------------------------------------------------------------------
__global__ __launch_bounds__(256)
void k_gather(const int* __restrict__ row_start,
              const int* __restrict__ cursor,
              const int* __restrict__ col,
              const float* __restrict__ s_src,
              const float* __restrict__ s_dst,
              const float* __restrict__ h,
              float* __restrict__ out)
{
    const int tid  = threadIdx.x;
    const int cg   = tid & 31;
    const int node = blockIdx.x * 8 + (tid >> 5);
    const int beg  = row_start[node];
    const int end  = cursor[node];
    const float ss = s_src[node];
    const float4* h4 = reinterpret_cast<const float4*>(h);

    float4 acc = {0.f, 0.f, 0.f, 0.f};
    int j = beg;
    for (; j + 1 < end; j += 2) {                    // 2-way unroll for ILP
        const int d0 = col[j];
        const int d1 = col[j + 1];
        const float x0 = ss + s_dst[d0];
        const float x1 = ss + s_dst[d1];
        const float e0 = x0 > 0.f ? x0 : ALPHA * x0;
        const float e1 = x1 > 0.f ? x1 : ALPHA * x1;
        const float4 hv0 = h4[(long long)d0 * 32 + cg];
        const float4 hv1 = h4[(long long)d1 * 32 + cg];
        acc.x += e0 * hv0.x + e1 * hv1.x;
        acc.y += e0 * hv0.y + e1 * hv1.y;
        acc.z += e0 * hv0.z + e1 * hv1.z;
        acc.w += e0 * hv0.w + e1 * hv1.w;
    }
    if (j < end) {
        const int d0 = col[j];
        const float x0 = ss + s_dst[d0];
        const float e0 = x0 > 0.f ? x0 : ALPHA * x0;
        const float4 hv0 = h4[(long long)d0 * 32 + cg];
        acc.x += e0 * hv0.x; acc.y += e0 * hv0.y;
        acc.z += e0 * hv0.z; acc.w += e0 * hv0.w;
    }
    reinterpret_cast<float4*>(out)[(long long)node * 32 + cg] = acc;
}

// ---------------------------------------------------------------------------
extern "C" void kernel_launch(void* const* d_in, const int* in_sizes, int n_in,
                              void* d_out, int out_size, void* d_ws, size_t ws_size,
                              hipStream_t stream) {
    const float* feat = (const float*)d_in[0];
    const float* W    = (const float*)d_in[1];
    const float* a    = (const float*)d_in[2];
    const float* bias = (const float*)d_in[3];
    const int*   adj  = (const int*)d_in[4];
    float* out = (float*)d_out;

    char* ws = (char*)d_ws;
    float* h         = (float*)(ws);                    // 25,600,000 B
    float* s_src     = (float*)(ws + 25600000);         //    200,000 B
    float* s_dst     = (float*)(ws + 25800000);         //    200,000 B
    int*   counts    = (int*)  (ws + 26000000);         //    200,000 B
    int*   row_start = (int*)  (ws + 26200000);         //    200,000 B
    int*   cursor    = (int*)  (ws + 26400000);         //    200,000 B
    int*   col       = (int*)  (ws + 26600000);         //  3,200,000 B

    hipMemsetAsync(counts, 0, N_NODES * sizeof(int), stream);

    k_gemm_scores<<<2048, 256, 0, stream>>>(feat, W, a, bias, h, s_src, s_dst);
    k_hist<<<(N_EDGES + 255) / 256, 256, 0, stream>>>(adj, counts);
    k_scan<<<1, 1024, 0, stream>>>(counts, row_start, cursor);
    k_fill<<<(N_EDGES + 255) / 256, 256, 0, stream>>>(adj, cursor, col);
    k_gather<<<N_NODES / 8, 256, 0, stream>>>(row_start, cursor, col,
                                              s_src, s_dst, h, out);
}

// Round 5
// 295.247 us; speedup vs baseline: 5.0744x; 1.3452x over previous
//
#include <hip/hip_runtime.h>

constexpr int N_NODES = 50000;
constexpr int N_EDGES = 800000;
constexpr int D = 128;
constexpr float ALPHA = 0.2f;
constexpr int GROUPS = N_NODES / 8;             // 6250 groups of 8 nodes (gemm)
constexpr int SCAN_NBLK = (N_NODES + 255) / 256; // 196

// ---------------------------------------------------------------------------
// K1: h = feat @ W + bias;  s_src[n] = h[n]·a[:128];  s_dst[n] = h[n]·a[128:]
// ---------------------------------------------------------------------------
__global__ __launch_bounds__(256)
void k_gemm_scores(const float* __restrict__ feat,
                   const float* __restrict__ W,
                   const float* __restrict__ a,
                   const float* __restrict__ bias,
                   float* __restrict__ h,
                   float* __restrict__ s_src,
                   float* __restrict__ s_dst)
{
    __shared__ float4 w_lds[D * 32];                 // 64 KB: [k][cg]
    const int tid = threadIdx.x;
    const float4* W4 = reinterpret_cast<const float4*>(W);
    for (int i = tid; i < D * 32; i += 256)
        w_lds[i] = W4[i];
    __syncthreads();

    const int cg = tid & 31;                         // column group (float4 index)
    const int ln = tid >> 5;                         // local node 0..7
    const float4 a_s = reinterpret_cast<const float4*>(a)[cg];
    const float4 a_d = reinterpret_cast<const float4*>(a)[32 + cg];
    const float4 b4  = reinterpret_cast<const float4*>(bias)[cg];

    for (int g = blockIdx.x; g < GROUPS; g += gridDim.x) {
        const int n = g * 8 + ln;
        const float* frow = feat + (long long)n * D;
        float4 acc = {0.f, 0.f, 0.f, 0.f};
        #pragma unroll 8
        for (int k = 0; k < D; ++k) {
            const float  f  = frow[k];               // broadcast across 32 lanes
            const float4 w4 = w_lds[k * 32 + cg];
            acc.x += f * w4.x; acc.y += f * w4.y;
            acc.z += f * w4.z; acc.w += f * w4.w;
        }
        acc.x += b4.x; acc.y += b4.y; acc.z += b4.z; acc.w += b4.w;
        reinterpret_cast<float4*>(h)[(long long)n * 32 + cg] = acc;

        float ps = acc.x * a_s.x + acc.y * a_s.y + acc.z * a_s.z + acc.w * a_s.w;
        float pd = acc.x * a_d.x + acc.y * a_d.y + acc.z * a_d.z + acc.w * a_d.w;
        #pragma unroll
        for (int m = 1; m < 32; m <<= 1) {
            ps += __shfl_xor(ps, m);
            pd += __shfl_xor(pd, m);
        }
        if (cg == 0) { s_src[n] = ps; s_dst[n] = pd; }
    }
}

// ---------------------------------------------------------------------------
// K2a: histogram edges by src
// ---------------------------------------------------------------------------
__global__ __launch_bounds__(256)
void k_hist(const int* __restrict__ adj, int* __restrict__ counts)
{
    const int i = blockIdx.x * 256 + threadIdx.x;
    if (i < N_EDGES) atomicAdd(&counts[adj[i]], 1);
}

// ---------------------------------------------------------------------------
// Block-wide inclusive scan of one int per thread (256 threads = 4 waves)
// ---------------------------------------------------------------------------
__device__ __forceinline__ int block_incl_scan(int v, int tid)
{
    __shared__ int wsum[4];
    const int lane = tid & 63;
    int x = v;
    #pragma unroll
    for (int off = 1; off < 64; off <<= 1) {
        const int y = __shfl_up(x, off);
        if (lane >= off) x += y;
    }
    if (lane == 63) wsum[tid >> 6] = x;
    __syncthreads();
    const int w = tid >> 6;
    int base = 0;
    #pragma unroll
    for (int k = 0; k < 3; ++k)
        if (k < w) base += wsum[k];
    return x + base;
}

// K2b-1: per-block inclusive scan; write inclusive values + block sums
__global__ __launch_bounds__(256)
void k_scan1(const int* __restrict__ counts,
             int* __restrict__ incl,
             int* __restrict__ bsum)
{
    const int i = blockIdx.x * 256 + threadIdx.x;
    const int v = (i < N_NODES) ? counts[i] : 0;
    const int x = block_incl_scan(v, threadIdx.x);
    if (i < N_NODES) incl[i] = x;
    if (threadIdx.x == 255) bsum[blockIdx.x] = x;
}

// K2b-2: single block scans the 196 block sums -> exclusive block bases
__global__ __launch_bounds__(256)
void k_scan2(const int* __restrict__ bsum, int* __restrict__ bbase)
{
    const int t = threadIdx.x;
    const int v = (t < SCAN_NBLK) ? bsum[t] : 0;
    const int x = block_incl_scan(v, t);
    if (t < SCAN_NBLK) bbase[t] = x - v;             // exclusive
}

// K2b-3: row_start = incl - count + bbase  (exclusive global scan)
__global__ __launch_bounds__(256)
void k_scan3(const int* __restrict__ incl,
             const int* __restrict__ counts,
             const int* __restrict__ bbase,
             int* __restrict__ row_start,
             int* __restrict__ cursor)
{
    const int i = blockIdx.x * 256 + threadIdx.x;
    if (i < N_NODES) {
        const int e = incl[i] - counts[i] + bbase[blockIdx.x];
        row_start[i] = e;
        cursor[i]    = e;
    }
}

// ---------------------------------------------------------------------------
// K2c: bucket fill — col[pos] = dst for each edge, bucketed by src
// ---------------------------------------------------------------------------
__global__ __launch_bounds__(256)
void k_fill(const int* __restrict__ adj,
            int* __restrict__ cursor,
            int* __restrict__ col)
{
    const int i = blockIdx.x * 256 + threadIdx.x;
    if (i < N_EDGES) {
        const int s = adj[i];
        const int d = adj[N_EDGES + i];
        const int pos = atomicAdd(&cursor[s], 1);
        col[pos] = d;
    }
}

// ---------------------------------------------------------------------------
// K3: gather — out[n] = sum over edges(n) of leaky(ss[n]+sd[dst]) * h[dst]
// 32 lanes per node, float4 per lane. One coalesced 512B store per node.
// ---------------------------------------------------------------------------
__global__ __launch_bounds__(256)
void k_gather(const int* __restrict__ row_start,
              const int* __restrict__ cursor,
              const int* __restrict__ col,
              const float* __restrict__ s_src,
              const float* __restrict__ s_dst,
              const float* __restrict__ h,
              float* __restrict__ out)
{
    const int tid  = threadIdx.x;
    const int cg   = tid & 31;
    const int node = blockIdx.x * 8 + (tid >> 5);
    const int beg  = row_start[node];
    const int end  = cursor[node];
    const float ss = s_src[node];
    const float4* h4 = reinterpret_cast<const float4*>(h);

    float4 acc = {0.f, 0.f, 0.f, 0.f};
    int j = beg;
    for (; j + 1 < end; j += 2) {
        const int d0 = col[j];
        const int d1 = col[j + 1];
        const float x0 = ss + s_dst[d0];
        const float x1 = ss + s_dst[d1];
        const float e0 = x0 > 0.f ? x0 : ALPHA * x0;
        const float e1 = x1 > 0.f ? x1 : ALPHA * x1;
        const float4 hv0 = h4[(long long)d0 * 32 + cg];
        const float4 hv1 = h4[(long long)d1 * 32 + cg];
        acc.x += e0 * hv0.x + e1 * hv1.x;
        acc.y += e0 * hv0.y + e1 * hv1.y;
        acc.z += e0 * hv0.z + e1 * hv1.z;
        acc.w += e0 * hv0.w + e1 * hv1.w;
    }
    if (j < end) {
        const int d0 = col[j];
        const float x0 = ss + s_dst[d0];
        const float e0 = x0 > 0.f ? x0 : ALPHA * x0;
        const float4 hv0 = h4[(long long)d0 * 32 + cg];
        acc.x += e0 * hv0.x; acc.y += e0 * hv0.y;
        acc.z += e0 * hv0.z; acc.w += e0 * hv0.w;
    }
    reinterpret_cast<float4*>(out)[(long long)node * 32 + cg] = acc;
}

// ---------------------------------------------------------------------------
extern "C" void kernel_launch(void* const* d_in, const int* in_sizes, int n_in,
                              void* d_out, int out_size, void* d_ws, size_t ws_size,
                              hipStream_t stream) {
    const float* feat = (const float*)d_in[0];
    const float* W    = (const float*)d_in[1];
    const float* a    = (const float*)d_in[2];
    const float* bias = (const float*)d_in[3];
    const int*   adj  = (const int*)d_in[4];
    float* out = (float*)d_out;

    char* ws = (char*)d_ws;
    float* h         = (float*)(ws);                    // 25,600,000 B
    float* s_src     = (float*)(ws + 25600000);         //    200,000 B
    float* s_dst     = (float*)(ws + 25800000);         //    200,000 B
    int*   counts    = (int*)  (ws + 26000000);         //    200,000 B
    int*   row_start = (int*)  (ws + 26200000);         //    200,000 B
    int*   cursor    = (int*)  (ws + 26400000);         //    200,000 B
    int*   col       = (int*)  (ws + 26600000);         //  3,200,000 B
    int*   incl      = col;                             // aliased: dead before k_fill
    int*   bsum      = (int*)  (ws + 29800000);         //        784 B
    int*   bbase     = (int*)  (ws + 29804096);         //        784 B

    hipMemsetAsync(counts, 0, N_NODES * sizeof(int), stream);

    k_gemm_scores<<<2048, 256, 0, stream>>>(feat, W, a, bias, h, s_src, s_dst);
    k_hist<<<(N_EDGES + 255) / 256, 256, 0, stream>>>(adj, counts);
    k_scan1<<<SCAN_NBLK, 256, 0, stream>>>(counts, incl, bsum);
    k_scan2<<<1, 256, 0, stream>>>(bsum, bbase);
    k_scan3<<<SCAN_NBLK, 256, 0, stream>>>(incl, counts, bbase, row_start, cursor);
    k_fill<<<(N_EDGES + 255) / 256, 256, 0, stream>>>(adj, cursor, col);
    k_gather<<<N_NODES / 8, 256, 0, stream>>>(row_start, cursor, col,
                                              s_src, s_dst, h, out);
}

// Round 9
// 270.219 us; speedup vs baseline: 5.5444x; 1.0926x over previous
//
#include <hip/hip_runtime.h>

constexpr int N_NODES = 50000;
constexpr int N_EDGES = 800000;
constexpr int D = 128;
constexpr float ALPHA = 0.2f;
constexpr int SCAN_NBLK = (N_NODES + 255) / 256; // 196
constexpr int GEMM_NBLK = (N_NODES + 31) / 32;   // 1563 (32 nodes/block)

__device__ __forceinline__ void fma4(float4& acc, float s, const float4& w) {
    acc.x += s * w.x; acc.y += s * w.y; acc.z += s * w.z; acc.w += s * w.w;
}
__device__ __forceinline__ float dot4(const float4& x, const float4& y) {
    return x.x * y.x + x.y * y.y + x.z * y.z + x.w * y.w;
}

// ---------------------------------------------------------------------------
// K1: h = feat @ W + bias;  s_src[n] = h[n]·a[:128];  s_dst[n] = h[n]·a[128:]
// 4 nodes/thread: 64 FMAs per 4 ds_read_b128 -> VALU-bound despite 2 blk/CU.
// ---------------------------------------------------------------------------
__global__ __launch_bounds__(256)
void k_gemm_scores(const float* __restrict__ feat,
                   const float* __restrict__ W,
                   const float* __restrict__ a,
                   const float* __restrict__ bias,
                   float* __restrict__ h,
                   float* __restrict__ s_src,
                   float* __restrict__ s_dst)
{
    __shared__ float4 w_lds[D * 32];                 // 64 KB: [k][cg]
    const int tid = threadIdx.x;
    const float4* W4 = reinterpret_cast<const float4*>(W);
    #pragma unroll
    for (int i = 0; i < 16; ++i)
        w_lds[tid + i * 256] = W4[tid + i * 256];
    __syncthreads();

    const int cg = tid & 31;                         // column group (float4)
    const int ng = tid >> 5;                         // node group 0..7
    const int n0 = blockIdx.x * 32 + ng * 4;

    const float4 a_s = reinterpret_cast<const float4*>(a)[cg];
    const float4 a_d = reinterpret_cast<const float4*>(a)[32 + cg];
    const float4 b4  = reinterpret_cast<const float4*>(bias)[cg];

    // clamp row pointers so tail threads read in-bounds (stores are guarded)
    const float4* fA = reinterpret_cast<const float4*>(feat) + (long long)min(n0 + 0, N_NODES - 1) * 32;
    const float4* fB = reinterpret_cast<const float4*>(feat) + (long long)min(n0 + 1, N_NODES - 1) * 32;
    const float4* fC = reinterpret_cast<const float4*>(feat) + (long long)min(n0 + 2, N_NODES - 1) * 32;
    const float4* fD = reinterpret_cast<const float4*>(feat) + (long long)min(n0 + 3, N_NODES - 1) * 32;

    float4 acc0 = {0.f, 0.f, 0.f, 0.f};
    float4 acc1 = {0.f, 0.f, 0.f, 0.f};
    float4 acc2 = {0.f, 0.f, 0.f, 0.f};
    float4 acc3 = {0.f, 0.f, 0.f, 0.f};

    #pragma unroll 4
    for (int kc = 0; kc < 32; ++kc) {                // 4 k-values per chunk
        const float4 fa = fA[kc];
        const float4 fb = fB[kc];
        const float4 fc = fC[kc];
        const float4 fd = fD[kc];
        const float4 w0 = w_lds[(kc * 4 + 0) * 32 + cg];
        const float4 w1 = w_lds[(kc * 4 + 1) * 32 + cg];
        const float4 w2 = w_lds[(kc * 4 + 2) * 32 + cg];
        const float4 w3 = w_lds[(kc * 4 + 3) * 32 + cg];
        fma4(acc0, fa.x, w0); fma4(acc0, fa.y, w1); fma4(acc0, fa.z, w2); fma4(acc0, fa.w, w3);
        fma4(acc1, fb.x, w0); fma4(acc1, fb.y, w1); fma4(acc1, fb.z, w2); fma4(acc1, fb.w, w3);
        fma4(acc2, fc.x, w0); fma4(acc2, fc.y, w1); fma4(acc2, fc.z, w2); fma4(acc2, fc.w, w3);
        fma4(acc3, fd.x, w0); fma4(acc3, fd.y, w1); fma4(acc3, fd.z, w2); fma4(acc3, fd.w, w3);
    }

    acc0.x += b4.x; acc0.y += b4.y; acc0.z += b4.z; acc0.w += b4.w;
    acc1.x += b4.x; acc1.y += b4.y; acc1.z += b4.z; acc1.w += b4.w;
    acc2.x += b4.x; acc2.y += b4.y; acc2.z += b4.z; acc2.w += b4.w;
    acc3.x += b4.x; acc3.y += b4.y; acc3.z += b4.z; acc3.w += b4.w;

    float4* h4 = reinterpret_cast<float4*>(h);
    if (n0 + 0 < N_NODES) h4[(long long)(n0 + 0) * 32 + cg] = acc0;
    if (n0 + 1 < N_NODES) h4[(long long)(n0 + 1) * 32 + cg] = acc1;
    if (n0 + 2 < N_NODES) h4[(long long)(n0 + 2) * 32 + cg] = acc2;
    if (n0 + 3 < N_NODES) h4[(long long)(n0 + 3) * 32 + cg] = acc3;

    float ps0 = dot4(acc0, a_s), pd0 = dot4(acc0, a_d);
    float ps1 = dot4(acc1, a_s), pd1 = dot4(acc1, a_d);
    float ps2 = dot4(acc2, a_s), pd2 = dot4(acc2, a_d);
    float ps3 = dot4(acc3, a_s), pd3 = dot4(acc3, a_d);
    #pragma unroll
    for (int m = 1; m < 32; m <<= 1) {               // reduce across the 32-lane group
        ps0 += __shfl_xor(ps0, m); pd0 += __shfl_xor(pd0, m);
        ps1 += __shfl_xor(ps1, m); pd1 += __shfl_xor(pd1, m);
        ps2 += __shfl_xor(ps2, m); pd2 += __shfl_xor(pd2, m);
        ps3 += __shfl_xor(ps3, m); pd3 += __shfl_xor(pd3, m);
    }
    if (cg == 0) {
        if (n0 + 0 < N_NODES) { s_src[n0 + 0] = ps0; s_dst[n0 + 0] = pd0; }
        if (n0 + 1 < N_NODES) { s_src[n0 + 1] = ps1; s_dst[n0 + 1] = pd1; }
        if (n0 + 2 < N_NODES) { s_src[n0 + 2] = ps2; s_dst[n0 + 2] = pd2; }
        if (n0 + 3 < N_NODES) { s_src[n0 + 3] = ps3; s_dst[n0 + 3] = pd3; }
    }
}

// ---------------------------------------------------------------------------
// K2a: histogram edges by src
// ---------------------------------------------------------------------------
__global__ __launch_bounds__(256)
void k_hist(const int* __restrict__ adj, int* __restrict__ counts)
{
    const int i = blockIdx.x * 256 + threadIdx.x;
    if (i < N_EDGES) atomicAdd(&counts[adj[i]], 1);
}

// ---------------------------------------------------------------------------
// Block-wide inclusive scan of one int per thread (256 threads = 4 waves)
// ---------------------------------------------------------------------------
__device__ __forceinline__ int block_incl_scan(int v, int tid)
{
    __shared__ int wsum[4];
    const int lane = tid & 63;
    int x = v;
    #pragma unroll
    for (int off = 1; off < 64; off <<= 1) {
        const int y = __shfl_up(x, off);
        if (lane >= off) x += y;
    }
    if (lane == 63) wsum[tid >> 6] = x;
    __syncthreads();
    const int w = tid >> 6;
    int base = 0;
    #pragma unroll
    for (int k = 0; k < 3; ++k)
        if (k < w) base += wsum[k];
    return x + base;
}

// K2b-1: per-block inclusive scan; write inclusive values + block sums
__global__ __launch_bounds__(256)
void k_scan1(const int* __restrict__ counts,
             int* __restrict__ incl,
             int* __restrict__ bsum)
{
    const int i = blockIdx.x * 256 + threadIdx.x;
    const int v = (i < N_NODES) ? counts[i] : 0;
    const int x = block_incl_scan(v, threadIdx.x);
    if (i < N_NODES) incl[i] = x;
    if (threadIdx.x == 255) bsum[blockIdx.x] = x;
}

// K2b-2: single block scans the 196 block sums -> exclusive block bases
__global__ __launch_bounds__(256)
void k_scan2(const int* __restrict__ bsum, int* __restrict__ bbase)
{
    const int t = threadIdx.x;
    const int v = (t < SCAN_NBLK) ? bsum[t] : 0;
    const int x = block_incl_scan(v, t);
    if (t < SCAN_NBLK) bbase[t] = x - v;             // exclusive
}

// K2b-3: row_start = incl - count + bbase  (exclusive global scan)
__global__ __launch_bounds__(256)
void k_scan3(const int* __restrict__ incl,
             const int* __restrict__ counts,
             const int* __restrict__ bbase,
             int* __restrict__ row_start,
             int* __restrict__ cursor)
{
    const int i = blockIdx.x * 256 + threadIdx.x;
    if (i < N_NODES) {
        const int e = incl[i] - counts[i] + bbase[blockIdx.x];
        row_start[i] = e;
        cursor[i]    = e;
    }
}

// ---------------------------------------------------------------------------
// K2c: bucket fill — col[pos] = dst for each edge, bucketed by src
// ---------------------------------------------------------------------------
__global__ __launch_bounds__(256)
void k_fill(const int* __restrict__ adj,
            int* __restrict__ cursor,
            int* __restrict__ col)
{
    const int i = blockIdx.x * 256 + threadIdx.x;
    if (i < N_EDGES) {
        const int s = adj[i];
        const int d = adj[N_EDGES + i];
        const int pos = atomicAdd(&cursor[s], 1);
        col[pos] = d;
    }
}

// ---------------------------------------------------------------------------
// K3: gather — out[n] = sum over edges(n) of leaky(ss[n]+sd[dst]) * h[dst]
// 32 lanes per node, float4 per lane. One coalesced 512B store per node.
// ---------------------------------------------------------------------------
__global__ __launch_bounds__(256)
void k_gather(const int* __restrict__ row_start,
              const int* __restrict__ cursor,
              const int* __restrict__ col,
              const float* __restrict__ s_src,
              const float* __restrict__ s_dst,
              const float* __restrict__ h,
              float* __restrict__ out)
{
    const int tid  = threadIdx.x;
    const int cg   = tid & 31;
    const int node = blockIdx.x * 8 + (tid >> 5);
    const int beg  = row_start[node];
    const int end  = cursor[node];
    const float ss = s_src[node];
    const float4* h4 = reinterpret_cast<const float4*>(h);

    float4 acc = {0.f, 0.f, 0.f, 0.f};
    int j = beg;
    for (; j + 1 < end; j += 2) {
        const int d0 = col[j];
        const int d1 = col[j + 1];
        const float x0 = ss + s_dst[d0];
        const float x1 = ss + s_dst[d1];
        const float e0 = x0 > 0.f ? x0 : ALPHA * x0;
        const float e1 = x1 > 0.f ? x1 : ALPHA * x1;
        const float4 hv0 = h4[(long long)d0 * 32 + cg];
        const float4 hv1 = h4[(long long)d1 * 32 + cg];
        acc.x += e0 * hv0.x + e1 * hv1.x;
        acc.y += e0 * hv0.y + e1 * hv1.y;
        acc.z += e0 * hv0.z + e1 * hv1.z;
        acc.w += e0 * hv0.w + e1 * hv1.w;
    }
    if (j < end) {
        const int d0 = col[j];
        const float x0 = ss + s_dst[d0];
        const float e0 = x0 > 0.f ? x0 : ALPHA * x0;
        const float4 hv0 = h4[(long long)d0 * 32 + cg];
        acc.x += e0 * hv0.x; acc.y += e0 * hv0.y;
        acc.z += e0 * hv0.z; acc.w += e0 * hv0.w;
    }
    reinterpret_cast<float4*>(out)[(long long)node * 32 + cg] = acc;
}

// ---------------------------------------------------------------------------
extern "C" void kernel_launch(void* const* d_in, const int* in_sizes, int n_in,
                              void* d_out, int out_size, void* d_ws, size_t ws_size,
                              hipStream_t stream) {
    const float* feat = (const float*)d_in[0];
    const float* W    = (const float*)d_in[1];
    const float* a    = (const float*)d_in[2];
    const float* bias = (const float*)d_in[3];
    const int*   adj  = (const int*)d_in[4];
    float* out = (float*)d_out;

    char* ws = (char*)d_ws;
    float* h         = (float*)(ws);                    // 25,600,000 B
    float* s_src     = (float*)(ws + 25600000);         //    200,000 B
    float* s_dst     = (float*)(ws + 25800000);         //    200,000 B
    int*   counts    = (int*)  (ws + 26000000);         //    200,000 B
    int*   row_start = (int*)  (ws + 26200000);         //    200,000 B
    int*   cursor    = (int*)  (ws + 26400000);         //    200,000 B
    int*   col       = (int*)  (ws + 26600000);         //  3,200,000 B
    int*   incl      = col;                             // aliased: dead before k_fill
    int*   bsum      = (int*)  (ws + 29800000);         //        784 B
    int*   bbase     = (int*)  (ws + 29804096);         //        784 B

    hipMemsetAsync(counts, 0, N_NODES * sizeof(int), stream);

    k_gemm_scores<<<GEMM_NBLK, 256, 0, stream>>>(feat, W, a, bias, h, s_src, s_dst);
    k_hist<<<(N_EDGES + 255) / 256, 256, 0, stream>>>(adj, counts);
    k_scan1<<<SCAN_NBLK, 256, 0, stream>>>(counts, incl, bsum);
    k_scan2<<<1, 256, 0, stream>>>(bsum, bbase);
    k_scan3<<<SCAN_NBLK, 256, 0, stream>>>(incl, counts, bbase, row_start, cursor);
    k_fill<<<(N_EDGES + 255) / 256, 256, 0, stream>>>(adj, cursor, col);
    k_gather<<<N_NODES / 8, 256, 0, stream>>>(row_start, cursor, col,
                                              s_src, s_dst, h, out);
}

// Round 11
// 254.074 us; speedup vs baseline: 5.8967x; 1.0635x over previous
//
#include <hip/hip_runtime.h>

constexpr int N_NODES = 50000;
constexpr int N_EDGES = 800000;
constexpr int D = 128;
constexpr float ALPHA = 0.2f;
constexpr int SCAN_NBLK = (N_NODES + 255) / 256; // 196
constexpr int GEMM_NBLK = (N_NODES + 31) / 32;   // 1563 (32 nodes/block)
constexpr int NXCD = 8;
constexpr int NODES_PER_G = N_NODES / NXCD;      // 6250 (divides evenly)
constexpr int EDGE_NBLK = (N_EDGES + 255) / 256; // 3125

__device__ __forceinline__ void fma4(float4& acc, float s, const float4& w) {
    acc.x += s * w.x; acc.y += s * w.y; acc.z += s * w.z; acc.w += s * w.w;
}
__device__ __forceinline__ float dot4(const float4& x, const float4& y) {
    return x.x * y.x + x.y * y.y + x.z * y.z + x.w * y.w;
}

// ---------------------------------------------------------------------------
// K1: h = feat @ W + bias;  s_src[n] = h[n]·a[:128];  s_dst[n] = h[n]·a[128:]
// 4 nodes/thread: 64 FMAs per 4 ds_read_b128 -> VALU-bound despite 2 blk/CU.
// ---------------------------------------------------------------------------
__global__ __launch_bounds__(256)
void k_gemm_scores(const float* __restrict__ feat,
                   const float* __restrict__ W,
                   const float* __restrict__ a,
                   const float* __restrict__ bias,
                   float* __restrict__ h,
                   float* __restrict__ s_src,
                   float* __restrict__ s_dst)
{
    __shared__ float4 w_lds[D * 32];                 // 64 KB: [k][cg]
    const int tid = threadIdx.x;
    const float4* W4 = reinterpret_cast<const float4*>(W);
    #pragma unroll
    for (int i = 0; i < 16; ++i)
        w_lds[tid + i * 256] = W4[tid + i * 256];
    __syncthreads();

    const int cg = tid & 31;                         // column group (float4)
    const int ng = tid >> 5;                         // node group 0..7
    const int n0 = blockIdx.x * 32 + ng * 4;

    const float4 a_s = reinterpret_cast<const float4*>(a)[cg];
    const float4 a_d = reinterpret_cast<const float4*>(a)[32 + cg];
    const float4 b4  = reinterpret_cast<const float4*>(bias)[cg];

    // clamp row pointers so tail threads read in-bounds (stores are guarded)
    const float4* fA = reinterpret_cast<const float4*>(feat) + (long long)min(n0 + 0, N_NODES - 1) * 32;
    const float4* fB = reinterpret_cast<const float4*>(feat) + (long long)min(n0 + 1, N_NODES - 1) * 32;
    const float4* fC = reinterpret_cast<const float4*>(feat) + (long long)min(n0 + 2, N_NODES - 1) * 32;
    const float4* fD = reinterpret_cast<const float4*>(feat) + (long long)min(n0 + 3, N_NODES - 1) * 32;

    float4 acc0 = {0.f, 0.f, 0.f, 0.f};
    float4 acc1 = {0.f, 0.f, 0.f, 0.f};
    float4 acc2 = {0.f, 0.f, 0.f, 0.f};
    float4 acc3 = {0.f, 0.f, 0.f, 0.f};

    #pragma unroll 4
    for (int kc = 0; kc < 32; ++kc) {                // 4 k-values per chunk
        const float4 fa = fA[kc];
        const float4 fb = fB[kc];
        const float4 fc = fC[kc];
        const float4 fd = fD[kc];
        const float4 w0 = w_lds[(kc * 4 + 0) * 32 + cg];
        const float4 w1 = w_lds[(kc * 4 + 1) * 32 + cg];
        const float4 w2 = w_lds[(kc * 4 + 2) * 32 + cg];
        const float4 w3 = w_lds[(kc * 4 + 3) * 32 + cg];
        fma4(acc0, fa.x, w0); fma4(acc0, fa.y, w1); fma4(acc0, fa.z, w2); fma4(acc0, fa.w, w3);
        fma4(acc1, fb.x, w0); fma4(acc1, fb.y, w1); fma4(acc1, fb.z, w2); fma4(acc1, fb.w, w3);
        fma4(acc2, fc.x, w0); fma4(acc2, fc.y, w1); fma4(acc2, fc.z, w2); fma4(acc2, fc.w, w3);
        fma4(acc3, fd.x, w0); fma4(acc3, fd.y, w1); fma4(acc3, fd.z, w2); fma4(acc3, fd.w, w3);
    }

    acc0.x += b4.x; acc0.y += b4.y; acc0.z += b4.z; acc0.w += b4.w;
    acc1.x += b4.x; acc1.y += b4.y; acc1.z += b4.z; acc1.w += b4.w;
    acc2.x += b4.x; acc2.y += b4.y; acc2.z += b4.z; acc2.w += b4.w;
    acc3.x += b4.x; acc3.y += b4.y; acc3.z += b4.z; acc3.w += b4.w;

    float4* h4 = reinterpret_cast<float4*>(h);
    if (n0 + 0 < N_NODES) h4[(long long)(n0 + 0) * 32 + cg] = acc0;
    if (n0 + 1 < N_NODES) h4[(long long)(n0 + 1) * 32 + cg] = acc1;
    if (n0 + 2 < N_NODES) h4[(long long)(n0 + 2) * 32 + cg] = acc2;
    if (n0 + 3 < N_NODES) h4[(long long)(n0 + 3) * 32 + cg] = acc3;

    float ps0 = dot4(acc0, a_s), pd0 = dot4(acc0, a_d);
    float ps1 = dot4(acc1, a_s), pd1 = dot4(acc1, a_d);
    float ps2 = dot4(acc2, a_s), pd2 = dot4(acc2, a_d);
    float ps3 = dot4(acc3, a_s), pd3 = dot4(acc3, a_d);
    #pragma unroll
    for (int m = 1; m < 32; m <<= 1) {               // reduce across the 32-lane group
        ps0 += __shfl_xor(ps0, m); pd0 += __shfl_xor(pd0, m);
        ps1 += __shfl_xor(ps1, m); pd1 += __shfl_xor(pd1, m);
        ps2 += __shfl_xor(ps2, m); pd2 += __shfl_xor(pd2, m);
        ps3 += __shfl_xor(ps3, m); pd3 += __shfl_xor(pd3, m);
    }
    if (cg == 0) {
        if (n0 + 0 < N_NODES) { s_src[n0 + 0] = ps0; s_dst[n0 + 0] = pd0; }
        if (n0 + 1 < N_NODES) { s_src[n0 + 1] = ps1; s_dst[n0 + 1] = pd1; }
        if (n0 + 2 < N_NODES) { s_src[n0 + 2] = ps2; s_dst[n0 + 2] = pd2; }
        if (n0 + 3 < N_NODES) { s_src[n0 + 3] = ps3; s_dst[n0 + 3] = pd3; }
    }
}

// ---------------------------------------------------------------------------
// K2a: histogram edges by src — XCD-range-partitioned.
// Block b handles node range g = b%8 (lands on XCD g under round-robin
// dispatch); counts[] lines for range g are touched by XCD g only ->
// no cross-XCD L2 line ping-pong. adj re-read 8x but L3-absorbed.
// ---------------------------------------------------------------------------
__global__ __launch_bounds__(256)
void k_hist(const int* __restrict__ adj, int* __restrict__ counts)
{
    const int g  = blockIdx.x & (NXCD - 1);
    const int eb = blockIdx.x >> 3;
    const int i  = eb * 256 + threadIdx.x;
    if (i >= N_EDGES) return;
    const int s = adj[i];
    if ((unsigned)(s - g * NODES_PER_G) < (unsigned)NODES_PER_G)
        atomicAdd(&counts[s], 1);
}

// ---------------------------------------------------------------------------
// Block-wide inclusive scan of one int per thread (256 threads = 4 waves)
// ---------------------------------------------------------------------------
__device__ __forceinline__ int block_incl_scan(int v, int tid)
{
    __shared__ int wsum[4];
    const int lane = tid & 63;
    int x = v;
    #pragma unroll
    for (int off = 1; off < 64; off <<= 1) {
        const int y = __shfl_up(x, off);
        if (lane >= off) x += y;
    }
    if (lane == 63) wsum[tid >> 6] = x;
    __syncthreads();
    const int w = tid >> 6;
    int base = 0;
    #pragma unroll
    for (int k = 0; k < 3; ++k)
        if (k < w) base += wsum[k];
    return x + base;
}

// K2b-1: per-block inclusive scan; write inclusive values + block sums
__global__ __launch_bounds__(256)
void k_scan1(const int* __restrict__ counts,
             int* __restrict__ incl,
             int* __restrict__ bsum)
{
    const int i = blockIdx.x * 256 + threadIdx.x;
    const int v = (i < N_NODES) ? counts[i] : 0;
    const int x = block_incl_scan(v, threadIdx.x);
    if (i < N_NODES) incl[i] = x;
    if (threadIdx.x == 255) bsum[blockIdx.x] = x;
}

// K2b-2: single block scans the 196 block sums -> exclusive block bases
__global__ __launch_bounds__(256)
void k_scan2(const int* __restrict__ bsum, int* __restrict__ bbase)
{
    const int t = threadIdx.x;
    const int v = (t < SCAN_NBLK) ? bsum[t] : 0;
    const int x = block_incl_scan(v, t);
    if (t < SCAN_NBLK) bbase[t] = x - v;             // exclusive
}

// K2b-3: row_start = incl - count + bbase  (exclusive global scan)
__global__ __launch_bounds__(256)
void k_scan3(const int* __restrict__ incl,
             const int* __restrict__ counts,
             const int* __restrict__ bbase,
             int* __restrict__ row_start,
             int* __restrict__ cursor)
{
    const int i = blockIdx.x * 256 + threadIdx.x;
    if (i < N_NODES) {
        const int e = incl[i] - counts[i] + bbase[blockIdx.x];
        row_start[i] = e;
        cursor[i]    = e;
    }
}

// ---------------------------------------------------------------------------
// K2c: bucket fill — XCD-range-partitioned (same scheme as k_hist).
// cursor[] atomics and col[] stores for node range g are issued by XCD g
// only -> col lines accumulate all ~16 stores in one L2, single writeback.
// Predicted: WRITE_SIZE 52.8 MB -> ~4-7 MB.
// ---------------------------------------------------------------------------
__global__ __launch_bounds__(256)
void k_fill(const int* __restrict__ adj,
            int* __restrict__ cursor,
            int* __restrict__ col)
{
    const int g  = blockIdx.x & (NXCD - 1);
    const int eb = blockIdx.x >> 3;
    const int i  = eb * 256 + threadIdx.x;
    if (i >= N_EDGES) return;
    const int s = adj[i];
    if ((unsigned)(s - g * NODES_PER_G) < (unsigned)NODES_PER_G) {
        const int d = adj[N_EDGES + i];
        const int pos = atomicAdd(&cursor[s], 1);
        col[pos] = d;
    }
}

// ---------------------------------------------------------------------------
// K3: gather — out[n] = sum over edges(n) of leaky(ss[n]+sd[dst]) * h[dst]
// 32 lanes per node, float4 per lane. One coalesced 512B store per node.
// ---------------------------------------------------------------------------
__global__ __launch_bounds__(256)
void k_gather(const int* __restrict__ row_start,
              const int* __restrict__ cursor,
              const int* __restrict__ col,
              const float* __restrict__ s_src,
              const float* __restrict__ s_dst,
              const float* __restrict__ h,
              float* __restrict__ out)
{
    const int tid  = threadIdx.x;
    const int cg   = tid & 31;
    const int node = blockIdx.x * 8 + (tid >> 5);
    const int beg  = row_start[node];
    const int end  = cursor[node];
    const float ss = s_src[node];
    const float4* h4 = reinterpret_cast<const float4*>(h);

    float4 acc = {0.f, 0.f, 0.f, 0.f};
    int j = beg;
    for (; j + 1 < end; j += 2) {
        const int d0 = col[j];
        const int d1 = col[j + 1];
        const float x0 = ss + s_dst[d0];
        const float x1 = ss + s_dst[d1];
        const float e0 = x0 > 0.f ? x0 : ALPHA * x0;
        const float e1 = x1 > 0.f ? x1 : ALPHA * x1;
        const float4 hv0 = h4[(long long)d0 * 32 + cg];
        const float4 hv1 = h4[(long long)d1 * 32 + cg];
        acc.x += e0 * hv0.x + e1 * hv1.x;
        acc.y += e0 * hv0.y + e1 * hv1.y;
        acc.z += e0 * hv0.z + e1 * hv1.z;
        acc.w += e0 * hv0.w + e1 * hv1.w;
    }
    if (j < end) {
        const int d0 = col[j];
        const float x0 = ss + s_dst[d0];
        const float e0 = x0 > 0.f ? x0 : ALPHA * x0;
        const float4 hv0 = h4[(long long)d0 * 32 + cg];
        acc.x += e0 * hv0.x; acc.y += e0 * hv0.y;
        acc.z += e0 * hv0.z; acc.w += e0 * hv0.w;
    }
    reinterpret_cast<float4*>(out)[(long long)node * 32 + cg] = acc;
}

// ---------------------------------------------------------------------------
extern "C" void kernel_launch(void* const* d_in, const int* in_sizes, int n_in,
                              void* d_out, int out_size, void* d_ws, size_t ws_size,
                              hipStream_t stream) {
    const float* feat = (const float*)d_in[0];
    const float* W    = (const float*)d_in[1];
    const float* a    = (const float*)d_in[2];
    const float* bias = (const float*)d_in[3];
    const int*   adj  = (const int*)d_in[4];
    float* out = (float*)d_out;

    char* ws = (char*)d_ws;
    float* h         = (float*)(ws);                    // 25,600,000 B
    float* s_src     = (float*)(ws + 25600000);         //    200,000 B
    float* s_dst     = (float*)(ws + 25800000);         //    200,000 B
    int*   counts    = (int*)  (ws + 26000000);         //    200,000 B
    int*   row_start = (int*)  (ws + 26200000);         //    200,000 B
    int*   cursor    = (int*)  (ws + 26400000);         //    200,000 B
    int*   col       = (int*)  (ws + 26600000);         //  3,200,000 B
    int*   incl      = col;                             // aliased: dead before k_fill
    int*   bsum      = (int*)  (ws + 29800000);         //        784 B
    int*   bbase     = (int*)  (ws + 29804096);         //        784 B

    hipMemsetAsync(counts, 0, N_NODES * sizeof(int), stream);

    k_gemm_scores<<<GEMM_NBLK, 256, 0, stream>>>(feat, W, a, bias, h, s_src, s_dst);
    k_hist<<<EDGE_NBLK * NXCD, 256, 0, stream>>>(adj, counts);
    k_scan1<<<SCAN_NBLK, 256, 0, stream>>>(counts, incl, bsum);
    k_scan2<<<1, 256, 0, stream>>>(bsum, bbase);
    k_scan3<<<SCAN_NBLK, 256, 0, stream>>>(incl, counts, bbase, row_start, cursor);
    k_fill<<<EDGE_NBLK * NXCD, 256, 0, stream>>>(adj, cursor, col);
    k_gather<<<N_NODES / 8, 256, 0, stream>>>(row_start, cursor, col,
                                              s_src, s_dst, h, out);
}

// Round 12
// 240.899 us; speedup vs baseline: 6.2192x; 1.0547x over previous
//
#include <hip/hip_runtime.h>

constexpr int N_NODES = 50000;
constexpr int N_EDGES = 800000;
constexpr int D = 128;
constexpr float ALPHA = 0.2f;
constexpr int SCAN_NBLK = (N_NODES + 255) / 256; // 196
constexpr int GEMM_NBLK = (N_NODES + 31) / 32;   // 1563 (32 nodes/block)
constexpr int NXCD = 8;
constexpr int NODES_PER_G = N_NODES / NXCD;      // 6250 (divides evenly)
constexpr int EDGE_NBLK = (N_EDGES + 255) / 256; // 3125

__device__ __forceinline__ void fma4(float4& acc, float s, const float4& w) {
    acc.x += s * w.x; acc.y += s * w.y; acc.z += s * w.z; acc.w += s * w.w;
}
__device__ __forceinline__ float dot4(const float4& x, const float4& y) {
    return x.x * y.x + x.y * y.y + x.z * y.z + x.w * y.w;
}
// pack two fp32 -> two bf16 (RNE) in one uint: low16 = a, high16 = b
__device__ __forceinline__ unsigned bf16pack2(float a, float b) {
    unsigned ua = __float_as_uint(a); ua += 0x7FFFu + ((ua >> 16) & 1u);
    unsigned ub = __float_as_uint(b); ub += 0x7FFFu + ((ub >> 16) & 1u);
    return (ua >> 16) | (ub & 0xFFFF0000u);
}
__device__ __forceinline__ float bf16lo(unsigned p) { return __uint_as_float(p << 16); }
__device__ __forceinline__ float bf16hi(unsigned p) { return __uint_as_float(p & 0xFFFF0000u); }

// ---------------------------------------------------------------------------
// K1: h_bf16 = bf16(feat @ W + bias);  s_src/s_dst from fp32 accumulators.
// h stored ONLY as bf16 (12.8 MB): halves gather traffic + 2x better L2 fit.
// ---------------------------------------------------------------------------
__global__ __launch_bounds__(256)
void k_gemm_scores(const float* __restrict__ feat,
                   const float* __restrict__ W,
                   const float* __restrict__ a,
                   const float* __restrict__ bias,
                   uint2* __restrict__ hb,
                   float* __restrict__ s_src,
                   float* __restrict__ s_dst)
{
    __shared__ float4 w_lds[D * 32];                 // 64 KB: [k][cg]
    const int tid = threadIdx.x;
    const float4* W4 = reinterpret_cast<const float4*>(W);
    #pragma unroll
    for (int i = 0; i < 16; ++i)
        w_lds[tid + i * 256] = W4[tid + i * 256];
    __syncthreads();

    const int cg = tid & 31;                         // column group (4 cols)
    const int ng = tid >> 5;                         // node group 0..7
    const int n0 = blockIdx.x * 32 + ng * 4;

    const float4 a_s = reinterpret_cast<const float4*>(a)[cg];
    const float4 a_d = reinterpret_cast<const float4*>(a)[32 + cg];
    const float4 b4  = reinterpret_cast<const float4*>(bias)[cg];

    // clamp row pointers so tail threads read in-bounds (stores are guarded)
    const float4* fA = reinterpret_cast<const float4*>(feat) + (long long)min(n0 + 0, N_NODES - 1) * 32;
    const float4* fB = reinterpret_cast<const float4*>(feat) + (long long)min(n0 + 1, N_NODES - 1) * 32;
    const float4* fC = reinterpret_cast<const float4*>(feat) + (long long)min(n0 + 2, N_NODES - 1) * 32;
    const float4* fD = reinterpret_cast<const float4*>(feat) + (long long)min(n0 + 3, N_NODES - 1) * 32;

    float4 acc0 = {0.f, 0.f, 0.f, 0.f};
    float4 acc1 = {0.f, 0.f, 0.f, 0.f};
    float4 acc2 = {0.f, 0.f, 0.f, 0.f};
    float4 acc3 = {0.f, 0.f, 0.f, 0.f};

    #pragma unroll 4
    for (int kc = 0; kc < 32; ++kc) {                // 4 k-values per chunk
        const float4 fa = fA[kc];
        const float4 fb = fB[kc];
        const float4 fc = fC[kc];
        const float4 fd = fD[kc];
        const float4 w0 = w_lds[(kc * 4 + 0) * 32 + cg];
        const float4 w1 = w_lds[(kc * 4 + 1) * 32 + cg];
        const float4 w2 = w_lds[(kc * 4 + 2) * 32 + cg];
        const float4 w3 = w_lds[(kc * 4 + 3) * 32 + cg];
        fma4(acc0, fa.x, w0); fma4(acc0, fa.y, w1); fma4(acc0, fa.z, w2); fma4(acc0, fa.w, w3);
        fma4(acc1, fb.x, w0); fma4(acc1, fb.y, w1); fma4(acc1, fb.z, w2); fma4(acc1, fb.w, w3);
        fma4(acc2, fc.x, w0); fma4(acc2, fc.y, w1); fma4(acc2, fc.z, w2); fma4(acc2, fc.w, w3);
        fma4(acc3, fd.x, w0); fma4(acc3, fd.y, w1); fma4(acc3, fd.z, w2); fma4(acc3, fd.w, w3);
    }

    acc0.x += b4.x; acc0.y += b4.y; acc0.z += b4.z; acc0.w += b4.w;
    acc1.x += b4.x; acc1.y += b4.y; acc1.z += b4.z; acc1.w += b4.w;
    acc2.x += b4.x; acc2.y += b4.y; acc2.z += b4.z; acc2.w += b4.w;
    acc3.x += b4.x; acc3.y += b4.y; acc3.z += b4.z; acc3.w += b4.w;

    if (n0 + 0 < N_NODES) hb[(long long)(n0 + 0) * 32 + cg] = make_uint2(bf16pack2(acc0.x, acc0.y), bf16pack2(acc0.z, acc0.w));
    if (n0 + 1 < N_NODES) hb[(long long)(n0 + 1) * 32 + cg] = make_uint2(bf16pack2(acc1.x, acc1.y), bf16pack2(acc1.z, acc1.w));
    if (n0 + 2 < N_NODES) hb[(long long)(n0 + 2) * 32 + cg] = make_uint2(bf16pack2(acc2.x, acc2.y), bf16pack2(acc2.z, acc2.w));
    if (n0 + 3 < N_NODES) hb[(long long)(n0 + 3) * 32 + cg] = make_uint2(bf16pack2(acc3.x, acc3.y), bf16pack2(acc3.z, acc3.w));

    float ps0 = dot4(acc0, a_s), pd0 = dot4(acc0, a_d);
    float ps1 = dot4(acc1, a_s), pd1 = dot4(acc1, a_d);
    float ps2 = dot4(acc2, a_s), pd2 = dot4(acc2, a_d);
    float ps3 = dot4(acc3, a_s), pd3 = dot4(acc3, a_d);
    #pragma unroll
    for (int m = 1; m < 32; m <<= 1) {               // reduce across the 32-lane group
        ps0 += __shfl_xor(ps0, m); pd0 += __shfl_xor(pd0, m);
        ps1 += __shfl_xor(ps1, m); pd1 += __shfl_xor(pd1, m);
        ps2 += __shfl_xor(ps2, m); pd2 += __shfl_xor(pd2, m);
        ps3 += __shfl_xor(ps3, m); pd3 += __shfl_xor(pd3, m);
    }
    if (cg == 0) {
        if (n0 + 0 < N_NODES) { s_src[n0 + 0] = ps0; s_dst[n0 + 0] = pd0; }
        if (n0 + 1 < N_NODES) { s_src[n0 + 1] = ps1; s_dst[n0 + 1] = pd1; }
        if (n0 + 2 < N_NODES) { s_src[n0 + 2] = ps2; s_dst[n0 + 2] = pd2; }
        if (n0 + 3 < N_NODES) { s_src[n0 + 3] = ps3; s_dst[n0 + 3] = pd3; }
    }
}

// ---------------------------------------------------------------------------
// K2a: histogram edges by src — XCD-range-partitioned (see round-9 note).
// ---------------------------------------------------------------------------
__global__ __launch_bounds__(256)
void k_hist(const int* __restrict__ adj, int* __restrict__ counts)
{
    const int g  = blockIdx.x & (NXCD - 1);
    const int eb = blockIdx.x >> 3;
    const int i  = eb * 256 + threadIdx.x;
    if (i >= N_EDGES) return;
    const int s = adj[i];
    if ((unsigned)(s - g * NODES_PER_G) < (unsigned)NODES_PER_G)
        atomicAdd(&counts[s], 1);
}

// ---------------------------------------------------------------------------
// Block-wide inclusive scan of one int per thread (256 threads = 4 waves)
// ---------------------------------------------------------------------------
__device__ __forceinline__ int block_incl_scan(int v, int tid)
{
    __shared__ int wsum[4];
    const int lane = tid & 63;
    int x = v;
    #pragma unroll
    for (int off = 1; off < 64; off <<= 1) {
        const int y = __shfl_up(x, off);
        if (lane >= off) x += y;
    }
    if (lane == 63) wsum[tid >> 6] = x;
    __syncthreads();
    const int w = tid >> 6;
    int base = 0;
    #pragma unroll
    for (int k = 0; k < 3; ++k)
        if (k < w) base += wsum[k];
    return x + base;
}

// K2b-1: per-block inclusive scan; write inclusive values + block sums
__global__ __launch_bounds__(256)
void k_scan1(const int* __restrict__ counts,
             int* __restrict__ incl,
             int* __restrict__ bsum)
{
    const int i = blockIdx.x * 256 + threadIdx.x;
    const int v = (i < N_NODES) ? counts[i] : 0;
    const int x = block_incl_scan(v, threadIdx.x);
    if (i < N_NODES) incl[i] = x;
    if (threadIdx.x == 255) bsum[blockIdx.x] = x;
}

// K2b-2: single block scans the 196 block sums -> exclusive block bases
__global__ __launch_bounds__(256)
void k_scan2(const int* __restrict__ bsum, int* __restrict__ bbase)
{
    const int t = threadIdx.x;
    const int v = (t < SCAN_NBLK) ? bsum[t] : 0;
    const int x = block_incl_scan(v, t);
    if (t < SCAN_NBLK) bbase[t] = x - v;             // exclusive
}

// K2b-3: row_start = incl - count + bbase  (exclusive global scan)
__global__ __launch_bounds__(256)
void k_scan3(const int* __restrict__ incl,
             const int* __restrict__ counts,
             const int* __restrict__ bbase,
             int* __restrict__ row_start,
             int* __restrict__ cursor)
{
    const int i = blockIdx.x * 256 + threadIdx.x;
    if (i < N_NODES) {
        const int e = incl[i] - counts[i] + bbase[blockIdx.x];
        row_start[i] = e;
        cursor[i]    = e;
    }
}

// ---------------------------------------------------------------------------
// K2c: bucket fill — XCD-range-partitioned (see round-9 note).
// ---------------------------------------------------------------------------
__global__ __launch_bounds__(256)
void k_fill(const int* __restrict__ adj,
            int* __restrict__ cursor,
            int* __restrict__ col)
{
    const int g  = blockIdx.x & (NXCD - 1);
    const int eb = blockIdx.x >> 3;
    const int i  = eb * 256 + threadIdx.x;
    if (i >= N_EDGES) return;
    const int s = adj[i];
    if ((unsigned)(s - g * NODES_PER_G) < (unsigned)NODES_PER_G) {
        const int d = adj[N_EDGES + i];
        const int pos = atomicAdd(&cursor[s], 1);
        col[pos] = d;
    }
}

// ---------------------------------------------------------------------------
// K3: gather — out[n] = sum over edges(n) of leaky(ss[n]+sd[dst]) * h[dst]
// h rows are bf16 (256 B): 32 lanes x uint2 (4 bf16 each). fp32 accumulate.
// ---------------------------------------------------------------------------
__global__ __launch_bounds__(256)
void k_gather(const int* __restrict__ row_start,
              const int* __restrict__ cursor,
              const int* __restrict__ col,
              const float* __restrict__ s_src,
              const float* __restrict__ s_dst,
              const uint2* __restrict__ hb,
              float* __restrict__ out)
{
    const int tid  = threadIdx.x;
    const int cg   = tid & 31;
    const int node = blockIdx.x * 8 + (tid >> 5);
    const int beg  = row_start[node];
    const int end  = cursor[node];
    const float ss = s_src[node];

    float4 acc = {0.f, 0.f, 0.f, 0.f};
    int j = beg;
    for (; j + 1 < end; j += 2) {
        const int d0 = col[j];
        const int d1 = col[j + 1];
        const float x0 = ss + s_dst[d0];
        const float x1 = ss + s_dst[d1];
        const float e0 = x0 > 0.f ? x0 : ALPHA * x0;
        const float e1 = x1 > 0.f ? x1 : ALPHA * x1;
        const uint2 p0 = hb[(long long)d0 * 32 + cg];
        const uint2 p1 = hb[(long long)d1 * 32 + cg];
        acc.x += e0 * bf16lo(p0.x) + e1 * bf16lo(p1.x);
        acc.y += e0 * bf16hi(p0.x) + e1 * bf16hi(p1.x);
        acc.z += e0 * bf16lo(p0.y) + e1 * bf16lo(p1.y);
        acc.w += e0 * bf16hi(p0.y) + e1 * bf16hi(p1.y);
    }
    if (j < end) {
        const int d0 = col[j];
        const float x0 = ss + s_dst[d0];
        const float e0 = x0 > 0.f ? x0 : ALPHA * x0;
        const uint2 p0 = hb[(long long)d0 * 32 + cg];
        acc.x += e0 * bf16lo(p0.x);
        acc.y += e0 * bf16hi(p0.x);
        acc.z += e0 * bf16lo(p0.y);
        acc.w += e0 * bf16hi(p0.y);
    }
    reinterpret_cast<float4*>(out)[(long long)node * 32 + cg] = acc;
}

// ---------------------------------------------------------------------------
extern "C" void kernel_launch(void* const* d_in, const int* in_sizes, int n_in,
                              void* d_out, int out_size, void* d_ws, size_t ws_size,
                              hipStream_t stream) {
    const float* feat = (const float*)d_in[0];
    const float* W    = (const float*)d_in[1];
    const float* a    = (const float*)d_in[2];
    const float* bias = (const float*)d_in[3];
    const int*   adj  = (const int*)d_in[4];
    float* out = (float*)d_out;

    char* ws = (char*)d_ws;
    uint2* hb        = (uint2*)(ws);                    // 12,800,000 B (bf16 h)
    float* s_src     = (float*)(ws + 25600000);         //    200,000 B
    float* s_dst     = (float*)(ws + 25800000);         //    200,000 B
    int*   counts    = (int*)  (ws + 26000000);         //    200,000 B
    int*   row_start = (int*)  (ws + 26200000);         //    200,000 B
    int*   cursor    = (int*)  (ws + 26400000);         //    200,000 B
    int*   col       = (int*)  (ws + 26600000);         //  3,200,000 B
    int*   incl      = col;                             // aliased: dead before k_fill
    int*   bsum      = (int*)  (ws + 29800000);         //        784 B
    int*   bbase     = (int*)  (ws + 29804096);         //        784 B

    hipMemsetAsync(counts, 0, N_NODES * sizeof(int), stream);

    k_gemm_scores<<<GEMM_NBLK, 256, 0, stream>>>(feat, W, a, bias, hb, s_src, s_dst);
    k_hist<<<EDGE_NBLK * NXCD, 256, 0, stream>>>(adj, counts);
    k_scan1<<<SCAN_NBLK, 256, 0, stream>>>(counts, incl, bsum);
    k_scan2<<<1, 256, 0, stream>>>(bsum, bbase);
    k_scan3<<<SCAN_NBLK, 256, 0, stream>>>(incl, counts, bbase, row_start, cursor);
    k_fill<<<EDGE_NBLK * NXCD, 256, 0, stream>>>(adj, cursor, col);
    k_gather<<<N_NODES / 8, 256, 0, stream>>>(row_start, cursor, col,
                                              s_src, s_dst, hb, out);
}